// Round 2
// baseline (406.319 us; speedup 1.0000x reference)
//
#include <hip/hip_runtime.h>
#include <math.h>

// E-Langevin sampler, fully fused: one kernel runs all 5 scan steps.
//  * rows independent -> one wave owns one row for the whole scan
//  * x binary -> x@W is a gather-sum of W rows; x_delta@W is an
//    incremental sparse update (~19.5 flipped bits/row/step)
//  * ROUND-2: the kernel is latency-bound on the W-row gathers (round-1
//    proved it is NOT L2-BW-bound: LDS-caching half of W was null).
//    Fix = deep memory-level parallelism with unchanged math:
//      - init: A/B double-buffered 8-wide batches (16 loads in flight)
//      - y2:   whole-group prefetch (up to 8 rows/group, static slots),
//              group i+1 fetched before group i is consumed, first two
//              groups fetched before the logf pass so latency hides
//    Consumption order stays strictly (i asc, j asc) per accumulator ->
//    bitwise-identical results (absmax must stay 0).
//  * gather accumulates packed as 2xfp32 (v_pk_add_f32 / v_pk_fma_f32):
//    identical rounding to scalar add/fmaf, half the VALU instructions
//  * rr/noise/x/xa loads and out stores are non-temporal so the ~200MB
//    streaming traffic does not evict W (256KB) from the XCD L2s

namespace {

constexpr int kB = 16384;
constexpr int kD = 256;
constexpr int kSteps = 5;

typedef float v2f __attribute__((ext_vector_type(2)));
typedef float v4f __attribute__((ext_vector_type(4)));

__device__ __forceinline__ v4f nt_load4(const float* p) {
  return __builtin_nontemporal_load(reinterpret_cast<const v4f*>(p));
}
__device__ __forceinline__ void nt_store4(float* p, v4f v) {
  __builtin_nontemporal_store(v, reinterpret_cast<v4f*>(p));
}

__device__ __forceinline__ float wave_sum(float v) {
#pragma unroll
  for (int off = 32; off > 0; off >>= 1) v += __shfl_xor(v, off, 64);
  return v;
}

__device__ __forceinline__ float sigmoid_f(float t) {
  if (t >= 0.0f) {
    float e = expf(-t);
    return 1.0f / (1.0f + e);
  } else {
    float e = expf(t);
    return e / (1.0f + e);
  }
}

__global__ __launch_bounds__(256) void els_fused(
    const float* __restrict__ x_in, const float* __restrict__ xa_in,
    const float* __restrict__ W, const float* __restrict__ bvec,
    const float* __restrict__ rr, const float* __restrict__ noise,
    const float* __restrict__ accept_u, float* __restrict__ out) {
  const int lane = threadIdx.x & 63;
  const int row = blockIdx.x * 4 + (threadIdx.x >> 6);  // 4 waves/block
  const int c0 = lane << 2;  // this lane owns columns c0..c0+3
  const float* __restrict__ Wc = W + c0;

  const v4f x4 = nt_load4(x_in + (size_t)row * kD + c0);
  const v4f a4 = nt_load4(xa_in + (size_t)row * kD + c0);
  const float4 b4 = *reinterpret_cast<const float4*>(bvec + c0);
  float xv[4] = {x4.x, x4.y, x4.z, x4.w};
  float xa[4] = {a4.x, a4.y, a4.z, a4.w};
  const float bv[4] = {b4.x, b4.y, b4.z, b4.w};
  v2f y01 = {0.0f, 0.0f}, y23 = {0.0f, 0.0f};

  // prefetch step 0 inputs (long latency hidden behind the init gather)
  v4f r4 = nt_load4(rr + (size_t)row * kD + c0);
  v4f n4 = nt_load4(noise + (size_t)row * kD + c0);
  float u = accept_u[row];

  // ---- init: y = x @ W, gather of W rows where x[d]==1.
  //      A/B double-buffered 8-wide batches: batch k+1's loads are in
  //      flight while batch k's adds run. FIFO order == ascending j ----
#pragma unroll
  for (int i = 0; i < 4; ++i) {
    unsigned long long m = __ballot(xv[i] > 0.5f);
    float4 bufA[8], bufB[8];
    int na = 0, nb = 0;
    auto fetch8 = [&](float4 (&buf)[8]) -> int {
      int n = 0;
#pragma unroll
      for (int q = 0; q < 8; ++q) {
        if (m) {  // wave-uniform scalar guard
          const int j = __builtin_ctzll(m); m &= m - 1;
          buf[q] = *reinterpret_cast<const float4*>(Wc + (size_t)(4 * j + i) * kD);
          ++n;
        }
      }
      return n;
    };
    auto cons8 = [&](const float4 (&buf)[8], int n) {
#pragma unroll
      for (int q = 0; q < 8; ++q)
        if (q < n) {
          y01 += (v2f){buf[q].x, buf[q].y};
          y23 += (v2f){buf[q].z, buf[q].w};
        }
    };
    na = fetch8(bufA);
    for (;;) {
      if (!m) { cons8(bufA, na); break; }
      nb = fetch8(bufB);
      cons8(bufA, na);
      if (!m) { cons8(bufB, nb); break; }
      na = fetch8(bufA);
      cons8(bufB, nb);
    }
  }

  for (int step = 0; step < kSteps; ++step) {
    // consume this step's prefetched inputs
    const float rrv[4] = {r4.x, r4.y, r4.z, r4.w};
    const float nzv[4] = {n4.x, n4.y, n4.z, n4.w};
    const float ucur = u;

    // prefetch NEXT step's inputs (issued now, consumed next iteration)
    const int sn = (step + 1 < kSteps) ? step + 1 : step;
    const size_t offn = ((size_t)sn * kB + row) * kD + c0;
    r4 = nt_load4(rr + offn);
    n4 = nt_load4(noise + offn);
    u = accept_u[(size_t)sn * kB + row];

    const float yv[4] = {y01.x, y01.y, y23.x, y23.y};
    float ga[4], xd[4], xda[4], pr[4];
    bool ind[4];
    unsigned long long fm[4], sm[4];

    // pass A: flip decisions + proposals
#pragma unroll
    for (int i = 0; i < 4; ++i) {
      ga[i] = (xv[i] - xa[i]) / 1.0e4f;                 // agrad, ETA=1e4
      const float sgn = 1.0f - 2.0f * xv[i];            // -(2x-1)
      const float gm = (yv[i] + bv[i] - ga[i]) * sgn / 2.0f;  // TEMP=2
      const float p = sigmoid_f(gm - 2.5f);             // term2 = 1/(2*0.2)
      ind[i] = rrv[i] < p;
      xd[i] = ind[i] ? 1.0f - xv[i] : xv[i];
      xda[i] = xa[i] + 0.25f * ga[i] + 0.70710678118654752f * nzv[i];
      pr[i] = ind[i] ? p : 1.0f - p;
      fm[i] = __ballot(ind[i]);
      sm[i] = __ballot(xv[i] > 0.5f);  // flip 1->0 subtracts the W row
    }

    // ---- y2 gather machinery: per-group prefetch into static slots.
    //      j's are wave-uniform (SGPRs); fetches are guarded scalar ops ----
    float4 wP[8], wQ[8];
    int jP[8], jQ[8];
    int nP = 0, nQ = 0;
    unsigned long long mP = 0, mQ = 0;
    auto gfetch = [&](int i, float4 (&wb)[8], int (&jb)[8], int& n,
                      unsigned long long& mr) {
      unsigned long long mm = fm[i];
      n = 0;
#pragma unroll
      for (int q = 0; q < 8; ++q) {
        if (mm) {
          const int j = __builtin_ctzll(mm); mm &= mm - 1;
          jb[q] = j;
          wb[q] = *reinterpret_cast<const float4*>(Wc + (size_t)(4 * j + i) * kD);
          ++n;
        }
      }
      mr = mm;  // leftover (cnt>8, rare) handled serially in gcons
    };

    v2f y2lo = y01, y2hi = y23;
    auto gcons = [&](int i, const float4 (&wb)[8], const int (&jb)[8], int n,
                     unsigned long long mr) {
#pragma unroll
      for (int q = 0; q < 8; ++q)
        if (q < n) {
          const float s = ((sm[i] >> jb[q]) & 1ull) ? -1.0f : 1.0f;
          const v2f sv = {s, s};
          y2lo = __builtin_elementwise_fma(sv, (v2f){wb[q].x, wb[q].y}, y2lo);
          y2hi = __builtin_elementwise_fma(sv, (v2f){wb[q].z, wb[q].w}, y2hi);
        }
      while (mr) {  // rare tail, strictly ascending continues
        const int j = __builtin_ctzll(mr); mr &= mr - 1;
        const float s = ((sm[i] >> j) & 1ull) ? -1.0f : 1.0f;
        const float4 w = *reinterpret_cast<const float4*>(Wc + (size_t)(4 * j + i) * kD);
        const v2f sv = {s, s};
        y2lo = __builtin_elementwise_fma(sv, (v2f){w.x, w.y}, y2lo);
        y2hi = __builtin_elementwise_fma(sv, (v2f){w.z, w.w}, y2hi);
      }
    };

    // issue the first two groups' loads; they fly under the logf pass
    gfetch(0, wP, jP, nP, mP);
    gfetch(1, wQ, jQ, nQ, mQ);

    // pass B: logf + quadratic sums (independent of the fetches)
    float s_lpf = 0.f, s_xy = 0.f, s_xb = 0.f, s_sqc = 0.f, s_fwd = 0.f;
#pragma unroll
    for (int i = 0; i < 4; ++i) {
      s_lpf += logf(pr[i] + 1e-10f);
      s_xy += xv[i] * yv[i];
      s_xb += xv[i] * bv[i];
      const float dc = xv[i] - xa[i];
      s_sqc += dc * dc;
      const float fw = xda[i] - (xa[i] + 0.25f * ga[i]);
      s_fwd += fw * fw;
    }

    // consume groups in order; always one group's loads in flight ahead
    gcons(0, wP, jP, nP, mP);
    gfetch(2, wP, jP, nP, mP);
    gcons(1, wQ, jQ, nQ, mQ);
    gfetch(3, wQ, jQ, nQ, mQ);
    gcons(2, wP, jP, nP, mP);
    gcons(3, wQ, jQ, nQ, mQ);

    const float y2v[4] = {y2lo.x, y2lo.y, y2hi.x, y2hi.y};
    float s_lpr = 0.f, s_xdy = 0.f, s_xdb = 0.f, s_sqn = 0.f, s_rev = 0.f;
#pragma unroll
    for (int i = 0; i < 4; ++i) {
      const float ga2 = (xd[i] - xda[i]) / 1.0e4f;
      const float sgn2 = 1.0f - 2.0f * xd[i];
      const float gm2 = (y2v[i] + bv[i] - ga2) * sgn2 / 2.0f;
      const float p2 = sigmoid_f(gm2 - 2.5f);
      const float pr2 = ind[i] ? p2 : 1.0f - p2;
      s_lpr += logf(pr2 + 1e-10f);
      s_xdy += xd[i] * y2v[i];
      s_xdb += xd[i] * bv[i];
      const float dn = xd[i] - xda[i];
      s_sqn += dn * dn;
      const float rv = xa[i] - (xda[i] + 0.25f * ga2);
      s_rev += rv * rv;
    }

    // row reductions (wave = row)
    s_lpf = wave_sum(s_lpf);
    s_lpr = wave_sum(s_lpr);
    s_xy = wave_sum(s_xy);
    s_xb = wave_sum(s_xb);
    s_xdy = wave_sum(s_xdy);
    s_xdb = wave_sum(s_xdb);
    s_sqc = wave_sum(s_sqc);
    s_sqn = wave_sum(s_sqn);
    s_rev = wave_sum(s_rev);
    s_fwd = wave_sum(s_fwd);

    const float E_cur = 0.5f * s_xy + s_xb;
    const float E_new = 0.5f * s_xdy + s_xdb;
    const float m_term = (E_new - s_sqn / 2.0e4f) - (E_cur - s_sqc / 2.0e4f);
    // add_rev = s_rev / (-2*ALPHA_A) = -s_rev ; add_fwd = -s_fwd
    const float la = m_term - s_rev + s_fwd + s_lpr - s_lpf;
    const bool acc = la > logf(ucur);

#pragma unroll
    for (int i = 0; i < 4; ++i) {
      xv[i] = acc ? xd[i] : xv[i];
      xa[i] = acc ? xda[i] : xa[i];
    }
    y01 = acc ? y2lo : y01;
    y23 = acc ? y2hi : y23;
  }

  const v4f ox = {xv[0], xv[1], xv[2], xv[3]};
  const v4f oa = {xa[0], xa[1], xa[2], xa[3]};
  nt_store4(out + (size_t)row * kD + c0, ox);
  nt_store4(out + (size_t)kB * kD + (size_t)row * kD + c0, oa);
}

}  // namespace

extern "C" void kernel_launch(void* const* d_in, const int* in_sizes, int n_in,
                              void* d_out, int out_size, void* d_ws, size_t ws_size,
                              hipStream_t stream) {
  const float* x = (const float*)d_in[0];
  const float* xa = (const float*)d_in[1];
  const float* W = (const float*)d_in[2];
  const float* b = (const float*)d_in[3];
  const float* rr = (const float*)d_in[4];
  const float* noise = (const float*)d_in[5];
  const float* au = (const float*)d_in[6];
  float* out = (float*)d_out;

  dim3 grid(kB / 4);
  dim3 block(256);
  hipLaunchKernelGGL(els_fused, grid, block, 0, stream, x, xa, W, b, rr, noise,
                     au, out);
}